// Round 1
// baseline (1355.892 us; speedup 1.0000x reference)
//
#include <hip/hip_runtime.h>

#define NN 100000
#define EE 1600000
#define HH 128
#define GG 64

// ---------------------------------------------------------------- degree / dis
__global__ __launch_bounds__(256) void count_kernel(const int* __restrict__ dst,
                                                    int* __restrict__ cnt) {
    int e = blockIdx.x * 256 + threadIdx.x;
    if (e < EE) atomicAdd(&cnt[dst[e]], 1);
}

__global__ __launch_bounds__(256) void dis_kernel(const int* __restrict__ cnt,
                                                  float* __restrict__ dis) {
    int i = blockIdx.x * 256 + threadIdx.x;
    if (i < NN) dis[i] = rsqrtf((float)cnt[i] + 1.0f);
}

// ---------------------------------------------------------------- scan (CSR row_start)
#define SCAN_EPB 1024
__global__ __launch_bounds__(256) void scan_block_kernel(const int* __restrict__ in,
                                                         int* __restrict__ out,
                                                         int* __restrict__ bsums) {
    __shared__ int sd[256];
    int t = threadIdx.x;
    int base = blockIdx.x * SCAN_EPB + t * 4;
    int v[4];
#pragma unroll
    for (int j = 0; j < 4; ++j) v[j] = (base + j < NN) ? in[base + j] : 0;
    int s = v[0] + v[1] + v[2] + v[3];
    sd[t] = s;
    __syncthreads();
    for (int off = 1; off < 256; off <<= 1) {
        int add = (t >= off) ? sd[t - off] : 0;
        __syncthreads();
        sd[t] += add;
        __syncthreads();
    }
    int ex = sd[t] - s;  // exclusive prefix for this thread within block
    int run = ex;
#pragma unroll
    for (int j = 0; j < 4; ++j) {
        if (base + j < NN) out[base + j] = run;
        run += v[j];
    }
    if (t == 255) bsums[blockIdx.x] = sd[255];
}

__global__ void scan_sums_kernel(int* __restrict__ bsums, int nb) {
    if (threadIdx.x == 0 && blockIdx.x == 0) {
        int run = 0;
        for (int i = 0; i < nb; ++i) {
            int v = bsums[i];
            bsums[i] = run;
            run += v;
        }
    }
}

__global__ __launch_bounds__(256) void scan_add_kernel(int* __restrict__ rs,
                                                       const int* __restrict__ bsums,
                                                       int* __restrict__ cursor) {
    int i = blockIdx.x * 256 + threadIdx.x;
    if (i < NN) {
        int v = rs[i] + bsums[i >> 10];
        rs[i] = v;
        cursor[i] = v;
    }
    if (i == 0) rs[NN] = EE;
}

// ---------------------------------------------------------------- CSR scatter
__global__ __launch_bounds__(256) void scatter_kernel(const int* __restrict__ src,
                                                      const int* __restrict__ dst,
                                                      const float* __restrict__ dis,
                                                      int* __restrict__ cursor,
                                                      int2* __restrict__ csr) {
    int e = blockIdx.x * 256 + threadIdx.x;
    if (e < EE) {
        int d = dst[e], s = src[e];
        int p = atomicAdd(&cursor[d], 1);
        csr[p] = make_int2(s, __float_as_int(dis[s]));
    }
}

// ---------------------------------------------------------------- aggregation
// out[n] = dis[n]*(sum_e dis[src]*h[src]) + dis[n]^2*h[n] (+ bias)
template <bool BIAS>
__global__ __launch_bounds__(256) void agg_kernel(const float* __restrict__ h,
                                                  const float* __restrict__ dis,
                                                  const int2* __restrict__ csr,
                                                  const int* __restrict__ rs,
                                                  const float* __restrict__ bias,
                                                  float* __restrict__ out) {
    int node = blockIdx.x * 4 + (threadIdx.x >> 6);
    int lane = threadIdx.x & 63;
    if (node >= NN) return;
    int beg = rs[node], end = rs[node + 1];
    float ax = 0.f, ay = 0.f;
    for (int e = beg; e < end; ++e) {
        int2 pr = csr[e];
        float w = __int_as_float(pr.y);
        float2 hv = *(const float2*)(h + (size_t)pr.x * HH + lane * 2);
        ax = fmaf(w, hv.x, ax);
        ay = fmaf(w, hv.y, ay);
    }
    float d = dis[node];
    float2 hn = *(const float2*)(h + (size_t)node * HH + lane * 2);
    float rx = d * ax + d * d * hn.x;
    float ry = d * ay + d * d * hn.y;
    if (BIAS) {
        rx += bias[lane * 2];
        ry += bias[lane * 2 + 1];
    }
    float2 r = make_float2(rx, ry);
    *(float2*)(out + (size_t)node * HH + lane * 2) = r;
}

// ---------------------------------------------------------------- GEMM  out[N,M] = A[N,K] @ W[K,M]
template <int K, int M, bool RELU, bool BIAS, bool ACCUM>
__global__ __launch_bounds__(256) void gemm_kernel(const float* __restrict__ A,
                                                   const float* __restrict__ W,
                                                   const float* __restrict__ bias,
                                                   float* __restrict__ out) {
    __shared__ float As[32][128];
    __shared__ float Bs[32][128];
    int tid = threadIdx.x;
    int tx = tid & 15, ty = tid >> 4;
    int row0 = blockIdx.x * 128;
    int col0 = blockIdx.y * 128;
    float c[8][8] = {};
    for (int k0 = 0; k0 < K; k0 += 32) {
        __syncthreads();
        // A tile: lane-per-row mapping -> conflict-free LDS stores (transposed)
#pragma unroll
        for (int i = 0; i < 4; ++i) {
            int L = tid + i * 256;
            int r = L & 127, kq = L >> 7;
            int rg = row0 + r;
            if (rg > NN - 1) rg = NN - 1;
            float4 v = *(const float4*)(A + (size_t)rg * K + k0 + kq * 4);
            As[kq * 4 + 0][r] = v.x;
            As[kq * 4 + 1][r] = v.y;
            As[kq * 4 + 2][r] = v.z;
            As[kq * 4 + 3][r] = v.w;
        }
        // B tile: row-contiguous
#pragma unroll
        for (int i = 0; i < 4; ++i) {
            int L = tid + i * 256;
            int n4 = L & 31, k = L >> 5;
            float4 v = *(const float4*)(W + (size_t)(k0 + k) * M + col0 + n4 * 4);
            *(float4*)&Bs[k][n4 * 4] = v;
        }
        __syncthreads();
#pragma unroll
        for (int k = 0; k < 32; ++k) {
            float4 a0 = *(const float4*)&As[k][ty * 8];
            float4 a1 = *(const float4*)&As[k][ty * 8 + 4];
            float4 b0 = *(const float4*)&Bs[k][tx * 8];
            float4 b1 = *(const float4*)&Bs[k][tx * 8 + 4];
            float a[8] = {a0.x, a0.y, a0.z, a0.w, a1.x, a1.y, a1.z, a1.w};
            float b[8] = {b0.x, b0.y, b0.z, b0.w, b1.x, b1.y, b1.z, b1.w};
#pragma unroll
            for (int ii = 0; ii < 8; ++ii)
#pragma unroll
                for (int jj = 0; jj < 8; ++jj)
                    c[ii][jj] = fmaf(a[ii], b[jj], c[ii][jj]);
        }
    }
#pragma unroll
    for (int ii = 0; ii < 8; ++ii) {
        int row = row0 + ty * 8 + ii;
        if (row >= NN) continue;
#pragma unroll
        for (int jq = 0; jq < 2; ++jq) {
            int col = col0 + tx * 8 + jq * 4;
            float4 v = make_float4(c[ii][jq * 4 + 0], c[ii][jq * 4 + 1],
                                   c[ii][jq * 4 + 2], c[ii][jq * 4 + 3]);
            if (BIAS) {
                v.x += bias[col + 0];
                v.y += bias[col + 1];
                v.z += bias[col + 2];
                v.w += bias[col + 3];
            }
            if (RELU) {
                v.x = fmaxf(v.x, 0.f);
                v.y = fmaxf(v.y, 0.f);
                v.z = fmaxf(v.z, 0.f);
                v.w = fmaxf(v.w, 0.f);
            }
            float* op = out + (size_t)row * M + col;
            if (ACCUM) {
                float4 o = *(const float4*)op;
                v.x += o.x;
                v.y += o.y;
                v.z += o.z;
                v.w += o.w;
            }
            *(float4*)op = v;
        }
    }
}

// ---------------------------------------------------------------- pooling
__global__ __launch_bounds__(128) void pool_partial_kernel(const float* __restrict__ y,
                                                           const int* __restrict__ batch,
                                                           float* __restrict__ P) {
    int c = threadIdx.x;
    int chunk = (NN + gridDim.x - 1) / gridDim.x;
    int n0 = blockIdx.x * chunk;
    int n1 = n0 + chunk;
    if (n1 > NN) n1 = NN;
    if (n0 >= NN) return;
    int curg = batch[n0];
    float acc = 0.f;
    for (int n = n0; n < n1; ++n) {
        int g = batch[n];
        if (g != curg) {
            atomicAdd(&P[curg * HH + c], acc);
            acc = 0.f;
            curg = g;
        }
        acc += y[(size_t)n * HH + c];
    }
    atomicAdd(&P[curg * HH + c], acc);
}

__global__ __launch_bounds__(128) void pool_final_kernel(const float* __restrict__ P,
                                                         const int* __restrict__ batch,
                                                         float* __restrict__ out) {
    int g = blockIdx.x, c = threadIdx.x;
    int lo = 0, hi = NN;
    while (lo < hi) {
        int m = (lo + hi) >> 1;
        if (batch[m] < g) lo = m + 1;
        else hi = m;
    }
    int start = lo;
    int lo2 = start, hi2 = NN;
    while (lo2 < hi2) {
        int m = (lo2 + hi2) >> 1;
        if (batch[m] < g + 1) lo2 = m + 1;
        else hi2 = m;
    }
    float cntg = (float)(lo2 - start);
    out[g * HH + c] = P[g * HH + c] / fmaxf(cntg, 1.f);
}

// ---------------------------------------------------------------- launch
extern "C" void kernel_launch(void* const* d_in, const int* in_sizes, int n_in,
                              void* d_out, int out_size, void* d_ws, size_t ws_size,
                              hipStream_t stream) {
    const float* x = (const float*)d_in[0];
    const int* ei = (const int*)d_in[1];  // [2,E]: src = ei[0..E), dst = ei[E..2E)
    const int* batch = (const int*)d_in[2];
    const float* W1 = (const float*)d_in[3];
    const float* b1 = (const float*)d_in[4];
    const float* W2 = (const float*)d_in[5];
    const float* b2 = (const float*)d_in[6];
    const float* W3 = (const float*)d_in[7];
    const float* b3 = (const float*)d_in[8];
    const float* W4 = (const float*)d_in[9];
    const float* b4 = (const float*)d_in[10];
    const float* Wl = (const float*)d_in[11];
    const float* bl = (const float*)d_in[12];
    float* out = (float*)d_out;

    char* p = (char*)d_ws;
    auto alloc = [&](size_t bytes) {
        void* r = (void*)p;
        p += (bytes + 255) & ~(size_t)255;
        return r;
    };
    int* cnt = (int*)alloc((size_t)NN * 4);
    int* rs = (int*)alloc((size_t)(NN + 1) * 4);
    int* cursor = (int*)alloc((size_t)NN * 4);
    float* dis = (float*)alloc((size_t)NN * 4);
    const int NB = (NN + SCAN_EPB - 1) / SCAN_EPB;  // 98
    int* bsums = (int*)alloc((size_t)NB * 4);
    int2* csr = (int2*)alloc((size_t)EE * 8);
    float* A = (float*)alloc((size_t)NN * 128 * 4);
    float* B = (float*)alloc((size_t)NN * 128 * 4);
    float* C = (float*)alloc((size_t)NN * 256 * 4);
    float* P = (float*)alloc((size_t)GG * HH * 4);

    const int* src = ei;
    const int* dst = ei + EE;

    hipMemsetAsync(cnt, 0, (size_t)NN * 4, stream);
    hipMemsetAsync(P, 0, (size_t)GG * HH * 4, stream);

    count_kernel<<<EE / 256, 256, 0, stream>>>(dst, cnt);
    dis_kernel<<<(NN + 255) / 256, 256, 0, stream>>>(cnt, dis);
    scan_block_kernel<<<NB, 256, 0, stream>>>(cnt, rs, bsums);
    scan_sums_kernel<<<1, 64, 0, stream>>>(bsums, NB);
    scan_add_kernel<<<(NN + 255) / 256, 256, 0, stream>>>(rs, bsums, cursor);
    scatter_kernel<<<EE / 256, 256, 0, stream>>>(src, dst, dis, cursor, csr);

    const int AGG_GRID = (NN + 3) / 4;
    const int GEMM_GX = (NN + 127) / 128;

    // conv1: t0 = Agg(x); x1 = relu(t0@W1 + b1)
    agg_kernel<false><<<AGG_GRID, 256, 0, stream>>>(x, dis, csr, rs, nullptr, A);
    gemm_kernel<128, 128, true, true, false><<<dim3(GEMM_GX, 1), 256, 0, stream>>>(A, W1, b1, B);
    // conv2
    agg_kernel<false><<<AGG_GRID, 256, 0, stream>>>(B, dis, csr, rs, nullptr, A);
    gemm_kernel<128, 128, true, true, false><<<dim3(GEMM_GX, 1), 256, 0, stream>>>(A, W2, b2, B);
    // conv3 (aggregate-first keeps gather at 128 channels)
    agg_kernel<false><<<AGG_GRID, 256, 0, stream>>>(B, dis, csr, rs, nullptr, A);
    gemm_kernel<128, 256, true, true, false><<<dim3(GEMM_GX, 2), 256, 0, stream>>>(A, W3, b3, C);
    // conv4 (matmul-first keeps gather at 128 channels)
    gemm_kernel<256, 128, false, false, false><<<dim3(GEMM_GX, 1), 256, 0, stream>>>(C, W4, nullptr, A);
    agg_kernel<true><<<AGG_GRID, 256, 0, stream>>>(A, dis, csr, rs, b4, B);
    // skip connection: y += x@Wl + bl
    gemm_kernel<128, 128, false, true, true><<<dim3(GEMM_GX, 1), 256, 0, stream>>>(x, Wl, bl, B);
    // mean pool
    pool_partial_kernel<<<512, 128, 0, stream>>>(B, batch, P);
    pool_final_kernel<<<GG, HH, 0, stream>>>(P, batch, out);
}

// Round 2
// 1152.038 us; speedup vs baseline: 1.1770x; 1.1770x over previous
//
#include <hip/hip_runtime.h>

#define NN 100000
#define EE 1600000
#define GG 64

typedef __attribute__((ext_vector_type(8))) short short8v;
typedef __attribute__((ext_vector_type(4))) float f32x4;

__device__ __forceinline__ unsigned short f2bf(float f) {
    unsigned u = __float_as_uint(f);
    u = (u + 0x7FFFu + ((u >> 16) & 1)) >> 16;
    return (unsigned short)u;
}
__device__ __forceinline__ float bf2f(unsigned short s) {
    return __uint_as_float((unsigned)s << 16);
}

// ---------------------------------------------------------------- degree / dis
__global__ __launch_bounds__(256) void count_kernel(const int* __restrict__ dst,
                                                    int* __restrict__ cnt) {
    int e = blockIdx.x * 256 + threadIdx.x;
    if (e < EE) atomicAdd(&cnt[dst[e]], 1);
}

__global__ __launch_bounds__(256) void dis_kernel(const int* __restrict__ cnt,
                                                  float* __restrict__ dis) {
    int i = blockIdx.x * 256 + threadIdx.x;
    if (i < NN) dis[i] = rsqrtf((float)cnt[i] + 1.0f);
}

// ---------------------------------------------------------------- scan (CSR row_start)
#define SCAN_EPB 1024
__global__ __launch_bounds__(256) void scan_block_kernel(const int* __restrict__ in,
                                                         int* __restrict__ out,
                                                         int* __restrict__ bsums) {
    __shared__ int sd[256];
    int t = threadIdx.x;
    int base = blockIdx.x * SCAN_EPB + t * 4;
    int v[4];
#pragma unroll
    for (int j = 0; j < 4; ++j) v[j] = (base + j < NN) ? in[base + j] : 0;
    int s = v[0] + v[1] + v[2] + v[3];
    sd[t] = s;
    __syncthreads();
    for (int off = 1; off < 256; off <<= 1) {
        int add = (t >= off) ? sd[t - off] : 0;
        __syncthreads();
        sd[t] += add;
        __syncthreads();
    }
    int ex = sd[t] - s;
    int run = ex;
#pragma unroll
    for (int j = 0; j < 4; ++j) {
        if (base + j < NN) out[base + j] = run;
        run += v[j];
    }
    if (t == 255) bsums[blockIdx.x] = sd[255];
}

__global__ void scan_sums_kernel(int* __restrict__ bsums, int nb) {
    if (threadIdx.x == 0 && blockIdx.x == 0) {
        int run = 0;
        for (int i = 0; i < nb; ++i) {
            int v = bsums[i];
            bsums[i] = run;
            run += v;
        }
    }
}

__global__ __launch_bounds__(256) void scan_add_kernel(int* __restrict__ rs,
                                                       const int* __restrict__ bsums,
                                                       int* __restrict__ cursor) {
    int i = blockIdx.x * 256 + threadIdx.x;
    if (i < NN) {
        int v = rs[i] + bsums[i >> 10];
        rs[i] = v;
        cursor[i] = v;
    }
    if (i == 0) rs[NN] = EE;
}

// ---------------------------------------------------------------- CSR scatter
__global__ __launch_bounds__(256) void scatter_kernel(const int* __restrict__ src,
                                                      const int* __restrict__ dst,
                                                      const float* __restrict__ dis,
                                                      int* __restrict__ cursor,
                                                      int2* __restrict__ csr) {
    int e = blockIdx.x * 256 + threadIdx.x;
    if (e < EE) {
        int d = dst[e], s = src[e];
        int p = atomicAdd(&cursor[d], 1);
        csr[p] = make_int2(s, __float_as_int(dis[s]));
    }
}

// ---------------------------------------------------------------- x -> bf16
__global__ __launch_bounds__(256) void cvt_kernel(const float* __restrict__ x,
                                                  unsigned short* __restrict__ xb) {
    size_t i = ((size_t)blockIdx.x * 256 + threadIdx.x) * 8;
    float4 a = *(const float4*)(x + i);
    float4 b = *(const float4*)(x + i + 4);
    short8v v;
    v[0] = (short)f2bf(a.x); v[1] = (short)f2bf(a.y);
    v[2] = (short)f2bf(a.z); v[3] = (short)f2bf(a.w);
    v[4] = (short)f2bf(b.x); v[5] = (short)f2bf(b.y);
    v[6] = (short)f2bf(b.z); v[7] = (short)f2bf(b.w);
    *(short8v*)(xb + i) = v;
}

// ---------------------------------------------------------------- weight packing (hi/lo bf16, MFMA B-fragment layout)
// layout: [ct][ks][lane][0..7]=hi, [8..15]=lo ; B[k][col], col=ct*16+(lane&15), k=ks*32+(lane>>4)*8+i
template <int K, int M>
__global__ __launch_bounds__(64) void packw_kernel(const float* __restrict__ W,
                                                   unsigned short* __restrict__ Wp) {
    const int NKS = K / 32;
    int ct = blockIdx.x / NKS, ks = blockIdx.x % NKS;
    int lane = threadIdx.x;
    int col = ct * 16 + (lane & 15);
    int kb = ks * 32 + (lane >> 4) * 8;
    unsigned short* o = Wp + ((size_t)(ct * NKS + ks) * 64 + lane) * 16;
#pragma unroll
    for (int i = 0; i < 8; ++i) {
        float f = W[(size_t)(kb + i) * M + col];
        unsigned short h = f2bf(f);
        unsigned short l = f2bf(f - bf2f(h));
        o[i] = h;
        o[8 + i] = l;
    }
}

// ---------------------------------------------------------------- MFMA GEMM  out[N,M] = A[N,K] @ W[K,M]
// ASPLIT: A is fp32, split into hi/lo bf16 (3 mfma). else A is bf16 (2 mfma).
template <int K, int M, bool ASPLIT, bool RELU, bool BIAS, bool ACCUM>
__global__ __launch_bounds__(256) void gemm_kernel(const void* __restrict__ Ain,
                                                   const unsigned short* __restrict__ Wp,
                                                   const float* __restrict__ bias,
                                                   void* __restrict__ out) {
    const int NKS = K / 32;
    int tid = threadIdx.x;
    int wave = tid >> 6, lane = tid & 63;
    int r0 = blockIdx.x * 64 + wave * 16;
    int ra = r0 + (lane & 15);
    if (ra > NN - 1) ra = NN - 1;

    short8v ah[NKS];
    short8v al[ASPLIT ? NKS : 1];
    if (ASPLIT) {
        const float* A = (const float*)Ain;
#pragma unroll
        for (int ks = 0; ks < NKS; ++ks) {
            const float* p = A + (size_t)ra * K + ks * 32 + (lane >> 4) * 8;
            float4 v0 = *(const float4*)p;
            float4 v1 = *(const float4*)(p + 4);
            float f[8] = {v0.x, v0.y, v0.z, v0.w, v1.x, v1.y, v1.z, v1.w};
#pragma unroll
            for (int i = 0; i < 8; ++i) {
                unsigned short h = f2bf(f[i]);
                ah[ks][i] = (short)h;
                al[ks][i] = (short)f2bf(f[i] - bf2f(h));
            }
        }
    } else {
        const unsigned short* A = (const unsigned short*)Ain;
#pragma unroll
        for (int ks = 0; ks < NKS; ++ks)
            ah[ks] = *(const short8v*)(A + (size_t)ra * K + ks * 32 + (lane >> 4) * 8);
    }

#pragma unroll
    for (int ct = 0; ct < 8; ++ct) {
        int ctg = blockIdx.y * 8 + ct;
        int col = ctg * 16 + (lane & 15);
        float b = BIAS ? bias[col] : 0.f;
        f32x4 acc;
        acc[0] = b; acc[1] = b; acc[2] = b; acc[3] = b;
#pragma unroll
        for (int ks = 0; ks < NKS; ++ks) {
            const short8v* p = (const short8v*)Wp + ((size_t)(ctg * NKS + ks) * 64 + lane) * 2;
            short8v bh = p[0], bl = p[1];
            acc = __builtin_amdgcn_mfma_f32_16x16x32_bf16(ah[ks], bh, acc, 0, 0, 0);
            acc = __builtin_amdgcn_mfma_f32_16x16x32_bf16(ah[ks], bl, acc, 0, 0, 0);
            if (ASPLIT)
                acc = __builtin_amdgcn_mfma_f32_16x16x32_bf16(al[ks], bh, acc, 0, 0, 0);
        }
#pragma unroll
        for (int i = 0; i < 4; ++i) {
            int row = r0 + (lane >> 4) * 4 + i;
            if (row >= NN) continue;
            float v = acc[i];
            if (RELU) v = fmaxf(v, 0.f);
            if (ACCUM) {
                float* Y = (float*)out;
                Y[(size_t)row * M + col] += v;
            } else {
                unsigned short* O = (unsigned short*)out;
                O[(size_t)row * M + col] = f2bf(v);
            }
        }
    }
}

// ---------------------------------------------------------------- aggregation (bf16 in)
// out[n] = dis[n]*(sum_e dis[src]*h[src]) + dis[n]^2*h[n] (+ bias)
template <int OUTMODE>  // 0: bf16 out ; 1: fp32 out + bias
__global__ __launch_bounds__(256) void aggb_kernel(const unsigned short* __restrict__ h,
                                                   const float* __restrict__ dis,
                                                   const int2* __restrict__ csr,
                                                   const int* __restrict__ rs,
                                                   const float* __restrict__ bias,
                                                   void* __restrict__ out) {
    int node = blockIdx.x * 4 + (threadIdx.x >> 6);
    int lane = threadIdx.x & 63;
    if (node >= NN) return;
    int beg = rs[node], end = rs[node + 1];
    const unsigned* hb = (const unsigned*)h;
    float ax = 0.f, ay = 0.f;
    for (int e = beg; e < end; ++e) {
        int2 pr = csr[e];
        float w = __int_as_float(pr.y);
        unsigned u = hb[(size_t)pr.x * 64 + lane];
        ax = fmaf(w, __uint_as_float(u << 16), ax);
        ay = fmaf(w, __uint_as_float(u & 0xFFFF0000u), ay);
    }
    float d = dis[node];
    unsigned us = hb[(size_t)node * 64 + lane];
    float rx = d * ax + d * d * __uint_as_float(us << 16);
    float ry = d * ay + d * d * __uint_as_float(us & 0xFFFF0000u);
    if (OUTMODE == 0) {
        unsigned o = (unsigned)f2bf(rx) | ((unsigned)f2bf(ry) << 16);
        ((unsigned*)out)[(size_t)node * 64 + lane] = o;
    } else {
        float2 r = make_float2(rx + bias[lane * 2], ry + bias[lane * 2 + 1]);
        ((float2*)out)[(size_t)node * 64 + lane] = r;
    }
}

// ---------------------------------------------------------------- pooling
__global__ __launch_bounds__(128) void pool_partial_kernel(const float* __restrict__ y,
                                                           const int* __restrict__ batch,
                                                           float* __restrict__ P) {
    int c = threadIdx.x;
    int chunk = (NN + gridDim.x - 1) / gridDim.x;
    int n0 = blockIdx.x * chunk;
    int n1 = n0 + chunk;
    if (n1 > NN) n1 = NN;
    if (n0 >= NN) return;
    int curg = batch[n0];
    float acc = 0.f;
    for (int n = n0; n < n1; ++n) {
        int g = batch[n];
        if (g != curg) {
            atomicAdd(&P[curg * 128 + c], acc);
            acc = 0.f;
            curg = g;
        }
        acc += y[(size_t)n * 128 + c];
    }
    atomicAdd(&P[curg * 128 + c], acc);
}

__global__ __launch_bounds__(128) void pool_final_kernel(const float* __restrict__ P,
                                                         const int* __restrict__ batch,
                                                         float* __restrict__ out) {
    int g = blockIdx.x, c = threadIdx.x;
    int lo = 0, hi = NN;
    while (lo < hi) {
        int m = (lo + hi) >> 1;
        if (batch[m] < g) lo = m + 1;
        else hi = m;
    }
    int start = lo;
    int lo2 = start, hi2 = NN;
    while (lo2 < hi2) {
        int m = (lo2 + hi2) >> 1;
        if (batch[m] < g + 1) lo2 = m + 1;
        else hi2 = m;
    }
    float cntg = (float)(lo2 - start);
    out[g * 128 + c] = P[g * 128 + c] / fmaxf(cntg, 1.f);
}

// ---------------------------------------------------------------- launch
extern "C" void kernel_launch(void* const* d_in, const int* in_sizes, int n_in,
                              void* d_out, int out_size, void* d_ws, size_t ws_size,
                              hipStream_t stream) {
    const float* x = (const float*)d_in[0];
    const int* ei = (const int*)d_in[1];
    const int* batch = (const int*)d_in[2];
    const float* W1 = (const float*)d_in[3];
    const float* b1 = (const float*)d_in[4];
    const float* W2 = (const float*)d_in[5];
    const float* b2 = (const float*)d_in[6];
    const float* W3 = (const float*)d_in[7];
    const float* b3 = (const float*)d_in[8];
    const float* W4 = (const float*)d_in[9];
    const float* b4 = (const float*)d_in[10];
    const float* Wl = (const float*)d_in[11];
    const float* bl = (const float*)d_in[12];
    float* out = (float*)d_out;

    char* p = (char*)d_ws;
    auto alloc = [&](size_t bytes) {
        void* r = (void*)p;
        p += (bytes + 255) & ~(size_t)255;
        return r;
    };
    int* cnt = (int*)alloc((size_t)NN * 4);
    int* rs = (int*)alloc((size_t)(NN + 1) * 4);
    int* cursor = (int*)alloc((size_t)NN * 4);
    float* dis = (float*)alloc((size_t)NN * 4);
    const int NB = (NN + SCAN_EPB - 1) / SCAN_EPB;
    int* bsums = (int*)alloc((size_t)NB * 4);
    int2* csr = (int2*)alloc((size_t)EE * 8);
    unsigned short* xb = (unsigned short*)alloc((size_t)NN * 128 * 2);
    unsigned short* AG = (unsigned short*)alloc((size_t)NN * 128 * 2);   // agg outputs (also conv4 gemm out)
    unsigned short* GM = (unsigned short*)alloc((size_t)NN * 128 * 2);   // gemm outputs
    unsigned short* H3 = (unsigned short*)alloc((size_t)NN * 256 * 2);   // conv3 out
    float* Y = (float*)alloc((size_t)NN * 128 * 4);
    unsigned short* W1p = (unsigned short*)alloc(8 * 4 * 64 * 16 * 2);
    unsigned short* W2p = (unsigned short*)alloc(8 * 4 * 64 * 16 * 2);
    unsigned short* W3p = (unsigned short*)alloc(16 * 4 * 64 * 16 * 2);
    unsigned short* W4p = (unsigned short*)alloc(8 * 8 * 64 * 16 * 2);
    unsigned short* Wlp = (unsigned short*)alloc(8 * 4 * 64 * 16 * 2);
    float* P = (float*)alloc((size_t)GG * 128 * 4);

    const int* src = ei;
    const int* dst = ei + EE;

    hipMemsetAsync(cnt, 0, (size_t)NN * 4, stream);
    hipMemsetAsync(P, 0, (size_t)GG * 128 * 4, stream);

    count_kernel<<<EE / 256, 256, 0, stream>>>(dst, cnt);
    dis_kernel<<<(NN + 255) / 256, 256, 0, stream>>>(cnt, dis);
    scan_block_kernel<<<NB, 256, 0, stream>>>(cnt, rs, bsums);
    scan_sums_kernel<<<1, 64, 0, stream>>>(bsums, NB);
    scan_add_kernel<<<(NN + 255) / 256, 256, 0, stream>>>(rs, bsums, cursor);
    scatter_kernel<<<EE / 256, 256, 0, stream>>>(src, dst, dis, cursor, csr);

    cvt_kernel<<<(NN * 128) / (256 * 8), 256, 0, stream>>>(x, xb);
    packw_kernel<128, 128><<<8 * 4, 64, 0, stream>>>(W1, W1p);
    packw_kernel<128, 128><<<8 * 4, 64, 0, stream>>>(W2, W2p);
    packw_kernel<128, 256><<<16 * 4, 64, 0, stream>>>(W3, W3p);
    packw_kernel<256, 128><<<8 * 8, 64, 0, stream>>>(W4, W4p);
    packw_kernel<128, 128><<<8 * 4, 64, 0, stream>>>(Wl, Wlp);

    const int AGG_GRID = (NN + 3) / 4;
    const int GX = (NN + 63) / 64;  // 1563

    // conv1
    aggb_kernel<0><<<AGG_GRID, 256, 0, stream>>>(xb, dis, csr, rs, nullptr, AG);
    gemm_kernel<128, 128, false, true, true, false><<<dim3(GX, 1), 256, 0, stream>>>(AG, W1p, b1, GM);
    // conv2
    aggb_kernel<0><<<AGG_GRID, 256, 0, stream>>>(GM, dis, csr, rs, nullptr, AG);
    gemm_kernel<128, 128, false, true, true, false><<<dim3(GX, 1), 256, 0, stream>>>(AG, W2p, b2, GM);
    // conv3 (aggregate-first keeps gather at 128 channels)
    aggb_kernel<0><<<AGG_GRID, 256, 0, stream>>>(GM, dis, csr, rs, nullptr, AG);
    gemm_kernel<128, 256, false, true, true, false><<<dim3(GX, 2), 256, 0, stream>>>(AG, W3p, b3, H3);
    // conv4 (matmul-first keeps gather at 128 channels)
    gemm_kernel<256, 128, false, false, false, false><<<dim3(GX, 1), 256, 0, stream>>>(H3, W4p, nullptr, AG);
    aggb_kernel<1><<<AGG_GRID, 256, 0, stream>>>(AG, dis, csr, rs, b4, Y);
    // skip: Y += x @ Wl + bl  (fp32 A, hi/lo split)
    gemm_kernel<128, 128, true, false, true, true><<<dim3(GX, 1), 256, 0, stream>>>(x, Wlp, bl, Y);
    // mean pool
    pool_partial_kernel<<<512, 128, 0, stream>>>(Y, batch, P);
    pool_final_kernel<<<GG, 128, 0, stream>>>(P, batch, out);
}

// Round 3
// 820.614 us; speedup vs baseline: 1.6523x; 1.4039x over previous
//
#include <hip/hip_runtime.h>

#define NN 100000
#define EE 1600000
#define GG 64

typedef __attribute__((ext_vector_type(8))) short short8v;
typedef __attribute__((ext_vector_type(4))) float f32x4;

__device__ __forceinline__ unsigned short f2bf(float f) {
    unsigned u = __float_as_uint(f);
    u = (u + 0x7FFFu + ((u >> 16) & 1)) >> 16;
    return (unsigned short)u;
}
__device__ __forceinline__ float bf2f(unsigned short s) {
    return __uint_as_float((unsigned)s << 16);
}

// ---------------------------------------------------------------- degree / dis
__global__ __launch_bounds__(256) void count_kernel(const int* __restrict__ dst,
                                                    int* __restrict__ cnt) {
    int e = blockIdx.x * 256 + threadIdx.x;
    if (e < EE) atomicAdd(&cnt[dst[e]], 1);
}

__global__ __launch_bounds__(256) void dis_kernel(const int* __restrict__ cnt,
                                                  float* __restrict__ dis) {
    int i = blockIdx.x * 256 + threadIdx.x;
    if (i < NN) dis[i] = rsqrtf((float)cnt[i] + 1.0f);
}

// ---------------------------------------------------------------- scan (CSR row_start)
#define SCAN_EPB 1024
__global__ __launch_bounds__(256) void scan_block_kernel(const int* __restrict__ in,
                                                         int* __restrict__ out,
                                                         int* __restrict__ bsums) {
    __shared__ int sd[256];
    int t = threadIdx.x;
    int base = blockIdx.x * SCAN_EPB + t * 4;
    int v[4];
#pragma unroll
    for (int j = 0; j < 4; ++j) v[j] = (base + j < NN) ? in[base + j] : 0;
    int s = v[0] + v[1] + v[2] + v[3];
    sd[t] = s;
    __syncthreads();
    for (int off = 1; off < 256; off <<= 1) {
        int add = (t >= off) ? sd[t - off] : 0;
        __syncthreads();
        sd[t] += add;
        __syncthreads();
    }
    int ex = sd[t] - s;
    int run = ex;
#pragma unroll
    for (int j = 0; j < 4; ++j) {
        if (base + j < NN) out[base + j] = run;
        run += v[j];
    }
    if (t == 255) bsums[blockIdx.x] = sd[255];
}

__global__ void scan_sums_kernel(int* __restrict__ bsums, int nb) {
    if (threadIdx.x == 0 && blockIdx.x == 0) {
        int run = 0;
        for (int i = 0; i < nb; ++i) {
            int v = bsums[i];
            bsums[i] = run;
            run += v;
        }
    }
}

__global__ __launch_bounds__(256) void scan_add_kernel(int* __restrict__ rs,
                                                       const int* __restrict__ bsums,
                                                       int* __restrict__ cursor) {
    int i = blockIdx.x * 256 + threadIdx.x;
    if (i < NN) {
        int v = rs[i] + bsums[i >> 10];
        rs[i] = v;
        cursor[i] = v;
    }
    if (i == 0) rs[NN] = EE;
}

// ---------------------------------------------------------------- CSR scatter
__global__ __launch_bounds__(256) void scatter_kernel(const int* __restrict__ src,
                                                      const int* __restrict__ dst,
                                                      const float* __restrict__ dis,
                                                      int* __restrict__ cursor,
                                                      int2* __restrict__ csr) {
    int e = blockIdx.x * 256 + threadIdx.x;
    if (e < EE) {
        int d = dst[e], s = src[e];
        int p = atomicAdd(&cursor[d], 1);
        csr[p] = make_int2(s, __float_as_int(dis[s]));
    }
}

// ---------------------------------------------------------------- x -> bf16
__global__ __launch_bounds__(256) void cvt_kernel(const float* __restrict__ x,
                                                  unsigned short* __restrict__ xb) {
    size_t i = ((size_t)blockIdx.x * 256 + threadIdx.x) * 8;
    float4 a = *(const float4*)(x + i);
    float4 b = *(const float4*)(x + i + 4);
    short8v v;
    v[0] = (short)f2bf(a.x); v[1] = (short)f2bf(a.y);
    v[2] = (short)f2bf(a.z); v[3] = (short)f2bf(a.w);
    v[4] = (short)f2bf(b.x); v[5] = (short)f2bf(b.y);
    v[6] = (short)f2bf(b.z); v[7] = (short)f2bf(b.w);
    *(short8v*)(xb + i) = v;
}

// ---------------------------------------------------------------- weight packing (hi/lo bf16, MFMA B-fragment layout)
template <int K, int M>
__global__ __launch_bounds__(64) void packw_kernel(const float* __restrict__ W,
                                                   unsigned short* __restrict__ Wp) {
    const int NKS = K / 32;
    int ct = blockIdx.x / NKS, ks = blockIdx.x % NKS;
    int lane = threadIdx.x;
    int col = ct * 16 + (lane & 15);
    int kb = ks * 32 + (lane >> 4) * 8;
    unsigned short* o = Wp + ((size_t)(ct * NKS + ks) * 64 + lane) * 16;
#pragma unroll
    for (int i = 0; i < 8; ++i) {
        float f = W[(size_t)(kb + i) * M + col];
        unsigned short h = f2bf(f);
        unsigned short l = f2bf(f - bf2f(h));
        o[i] = h;
        o[8 + i] = l;
    }
}

// ---------------------------------------------------------------- MFMA GEMM  out[N,M] = A[N,K] @ W[K,M]
template <int K, int M, bool ASPLIT, bool RELU, bool BIAS, bool ACCUM>
__global__ __launch_bounds__(256) void gemm_kernel(const void* __restrict__ Ain,
                                                   const unsigned short* __restrict__ Wp,
                                                   const float* __restrict__ bias,
                                                   void* __restrict__ out) {
    const int NKS = K / 32;
    int tid = threadIdx.x;
    int wave = tid >> 6, lane = tid & 63;
    int r0 = blockIdx.x * 64 + wave * 16;
    int ra = r0 + (lane & 15);
    if (ra > NN - 1) ra = NN - 1;

    short8v ah[NKS];
    short8v al[ASPLIT ? NKS : 1];
    if (ASPLIT) {
        const float* A = (const float*)Ain;
#pragma unroll
        for (int ks = 0; ks < NKS; ++ks) {
            const float* p = A + (size_t)ra * K + ks * 32 + (lane >> 4) * 8;
            float4 v0 = *(const float4*)p;
            float4 v1 = *(const float4*)(p + 4);
            float f[8] = {v0.x, v0.y, v0.z, v0.w, v1.x, v1.y, v1.z, v1.w};
#pragma unroll
            for (int i = 0; i < 8; ++i) {
                unsigned short h = f2bf(f[i]);
                ah[ks][i] = (short)h;
                al[ks][i] = (short)f2bf(f[i] - bf2f(h));
            }
        }
    } else {
        const unsigned short* A = (const unsigned short*)Ain;
#pragma unroll
        for (int ks = 0; ks < NKS; ++ks)
            ah[ks] = *(const short8v*)(A + (size_t)ra * K + ks * 32 + (lane >> 4) * 8);
    }

#pragma unroll
    for (int ct = 0; ct < 8; ++ct) {
        int ctg = blockIdx.y * 8 + ct;
        int col = ctg * 16 + (lane & 15);
        float b = BIAS ? bias[col] : 0.f;
        f32x4 acc;
        acc[0] = b; acc[1] = b; acc[2] = b; acc[3] = b;
#pragma unroll
        for (int ks = 0; ks < NKS; ++ks) {
            const short8v* p = (const short8v*)Wp + ((size_t)(ctg * NKS + ks) * 64 + lane) * 2;
            short8v bh = p[0], bl = p[1];
            acc = __builtin_amdgcn_mfma_f32_16x16x32_bf16(ah[ks], bh, acc, 0, 0, 0);
            acc = __builtin_amdgcn_mfma_f32_16x16x32_bf16(ah[ks], bl, acc, 0, 0, 0);
            if (ASPLIT)
                acc = __builtin_amdgcn_mfma_f32_16x16x32_bf16(al[ks], bh, acc, 0, 0, 0);
        }
#pragma unroll
        for (int i = 0; i < 4; ++i) {
            int row = r0 + (lane >> 4) * 4 + i;
            if (row >= NN) continue;
            float v = acc[i];
            if (RELU) v = fmaxf(v, 0.f);
            if (ACCUM) {
                float* Y = (float*)out;
                Y[(size_t)row * M + col] += v;
            } else {
                unsigned short* O = (unsigned short*)out;
                O[(size_t)row * M + col] = f2bf(v);
            }
        }
    }
}

// ---------------------------------------------------------------- aggregation (bf16 in)
// wave = 1 node; lane = (slot s = lane>>4) x (chunk c = lane&15)
// slot s handles edges beg+4k+s; chunk c handles channels c*8..c*8+7 (16B uint4)
// out[n] = dis[n]*(sum_e dis[src]*h[src]) + dis[n]^2*h[n] (+ bias)
template <int OUTMODE>  // 0: bf16 out ; 1: fp32 out + bias
__global__ __launch_bounds__(256) void aggb_kernel(const unsigned short* __restrict__ h,
                                                   const float* __restrict__ dis,
                                                   const int2* __restrict__ csr,
                                                   const int* __restrict__ rs,
                                                   const float* __restrict__ bias,
                                                   void* __restrict__ out) {
    int node = blockIdx.x * 4 + (threadIdx.x >> 6);
    int lane = threadIdx.x & 63;
    if (node >= NN) return;
    int c = lane & 15;
    int s = lane >> 4;
    int beg = rs[node], end = rs[node + 1];
    const uint4* hb = (const uint4*)h;  // one row = 16 uint4 (128 bf16)
    float acc[8] = {};
    for (int e0 = beg; e0 < end; e0 += 4) {
        int e = e0 + s;
        int ec = e < end ? e : end - 1;
        int2 pr = csr[ec];
        float w = e < end ? __int_as_float(pr.y) : 0.f;
        uint4 v = hb[(size_t)pr.x * 16 + c];
        acc[0] = fmaf(w, __uint_as_float(v.x << 16), acc[0]);
        acc[1] = fmaf(w, __uint_as_float(v.x & 0xFFFF0000u), acc[1]);
        acc[2] = fmaf(w, __uint_as_float(v.y << 16), acc[2]);
        acc[3] = fmaf(w, __uint_as_float(v.y & 0xFFFF0000u), acc[3]);
        acc[4] = fmaf(w, __uint_as_float(v.z << 16), acc[4]);
        acc[5] = fmaf(w, __uint_as_float(v.z & 0xFFFF0000u), acc[5]);
        acc[6] = fmaf(w, __uint_as_float(v.w << 16), acc[6]);
        acc[7] = fmaf(w, __uint_as_float(v.w & 0xFFFF0000u), acc[7]);
    }
#pragma unroll
    for (int i = 0; i < 8; ++i) {
        acc[i] += __shfl_xor(acc[i], 16, 64);
        acc[i] += __shfl_xor(acc[i], 32, 64);
    }
    if (s == 0) {
        float d = dis[node];
        float dd = d * d;
        uint4 us = hb[(size_t)node * 16 + c];
        float sf[8];
        sf[0] = __uint_as_float(us.x << 16); sf[1] = __uint_as_float(us.x & 0xFFFF0000u);
        sf[2] = __uint_as_float(us.y << 16); sf[3] = __uint_as_float(us.y & 0xFFFF0000u);
        sf[4] = __uint_as_float(us.z << 16); sf[5] = __uint_as_float(us.z & 0xFFFF0000u);
        sf[6] = __uint_as_float(us.w << 16); sf[7] = __uint_as_float(us.w & 0xFFFF0000u);
        float r[8];
#pragma unroll
        for (int i = 0; i < 8; ++i) r[i] = fmaf(d, acc[i], dd * sf[i]);
        if (OUTMODE == 0) {
            uint4 o;
            o.x = (unsigned)f2bf(r[0]) | ((unsigned)f2bf(r[1]) << 16);
            o.y = (unsigned)f2bf(r[2]) | ((unsigned)f2bf(r[3]) << 16);
            o.z = (unsigned)f2bf(r[4]) | ((unsigned)f2bf(r[5]) << 16);
            o.w = (unsigned)f2bf(r[6]) | ((unsigned)f2bf(r[7]) << 16);
            ((uint4*)out)[(size_t)node * 16 + c] = o;
        } else {
#pragma unroll
            for (int i = 0; i < 8; ++i) r[i] += bias[c * 8 + i];
            float4 o0 = make_float4(r[0], r[1], r[2], r[3]);
            float4 o1 = make_float4(r[4], r[5], r[6], r[7]);
            float* O = (float*)out + (size_t)node * 128 + c * 8;
            *(float4*)O = o0;
            *(float4*)(O + 4) = o1;
        }
    }
}

// ---------------------------------------------------------------- pooling
__global__ __launch_bounds__(128) void pool_partial_kernel(const float* __restrict__ y,
                                                           const int* __restrict__ batch,
                                                           float* __restrict__ P) {
    int c = threadIdx.x;
    int chunk = (NN + gridDim.x - 1) / gridDim.x;
    int n0 = blockIdx.x * chunk;
    int n1 = n0 + chunk;
    if (n1 > NN) n1 = NN;
    if (n0 >= NN) return;
    int curg = batch[n0];
    float acc = 0.f;
    for (int n = n0; n < n1; ++n) {
        int g = batch[n];
        if (g != curg) {
            atomicAdd(&P[curg * 128 + c], acc);
            acc = 0.f;
            curg = g;
        }
        acc += y[(size_t)n * 128 + c];
    }
    atomicAdd(&P[curg * 128 + c], acc);
}

__global__ __launch_bounds__(128) void pool_final_kernel(const float* __restrict__ P,
                                                         const int* __restrict__ batch,
                                                         float* __restrict__ out) {
    int g = blockIdx.x, c = threadIdx.x;
    int lo = 0, hi = NN;
    while (lo < hi) {
        int m = (lo + hi) >> 1;
        if (batch[m] < g) lo = m + 1;
        else hi = m;
    }
    int start = lo;
    int lo2 = start, hi2 = NN;
    while (lo2 < hi2) {
        int m = (lo2 + hi2) >> 1;
        if (batch[m] < g + 1) lo2 = m + 1;
        else hi2 = m;
    }
    float cntg = (float)(lo2 - start);
    out[g * 128 + c] = P[g * 128 + c] / fmaxf(cntg, 1.f);
}

// ---------------------------------------------------------------- launch
extern "C" void kernel_launch(void* const* d_in, const int* in_sizes, int n_in,
                              void* d_out, int out_size, void* d_ws, size_t ws_size,
                              hipStream_t stream) {
    const float* x = (const float*)d_in[0];
    const int* ei = (const int*)d_in[1];
    const int* batch = (const int*)d_in[2];
    const float* W1 = (const float*)d_in[3];
    const float* b1 = (const float*)d_in[4];
    const float* W2 = (const float*)d_in[5];
    const float* b2 = (const float*)d_in[6];
    const float* W3 = (const float*)d_in[7];
    const float* b3 = (const float*)d_in[8];
    const float* W4 = (const float*)d_in[9];
    const float* b4 = (const float*)d_in[10];
    const float* Wl = (const float*)d_in[11];
    const float* bl = (const float*)d_in[12];
    float* out = (float*)d_out;

    char* p = (char*)d_ws;
    auto alloc = [&](size_t bytes) {
        void* r = (void*)p;
        p += (bytes + 255) & ~(size_t)255;
        return r;
    };
    int* cnt = (int*)alloc((size_t)NN * 4);
    int* rs = (int*)alloc((size_t)(NN + 1) * 4);
    int* cursor = (int*)alloc((size_t)NN * 4);
    float* dis = (float*)alloc((size_t)NN * 4);
    const int NB = (NN + SCAN_EPB - 1) / SCAN_EPB;
    int* bsums = (int*)alloc((size_t)NB * 4);
    int2* csr = (int2*)alloc((size_t)EE * 8);
    unsigned short* xb = (unsigned short*)alloc((size_t)NN * 128 * 2);
    unsigned short* AG = (unsigned short*)alloc((size_t)NN * 128 * 2);
    unsigned short* GM = (unsigned short*)alloc((size_t)NN * 128 * 2);
    unsigned short* H3 = (unsigned short*)alloc((size_t)NN * 256 * 2);
    float* Y = (float*)alloc((size_t)NN * 128 * 4);
    unsigned short* W1p = (unsigned short*)alloc(8 * 4 * 64 * 16 * 2);
    unsigned short* W2p = (unsigned short*)alloc(8 * 4 * 64 * 16 * 2);
    unsigned short* W3p = (unsigned short*)alloc(16 * 4 * 64 * 16 * 2);
    unsigned short* W4p = (unsigned short*)alloc(8 * 8 * 64 * 16 * 2);
    unsigned short* Wlp = (unsigned short*)alloc(8 * 4 * 64 * 16 * 2);
    float* P = (float*)alloc((size_t)GG * 128 * 4);

    const int* src = ei;
    const int* dst = ei + EE;

    hipMemsetAsync(cnt, 0, (size_t)NN * 4, stream);
    hipMemsetAsync(P, 0, (size_t)GG * 128 * 4, stream);

    count_kernel<<<EE / 256, 256, 0, stream>>>(dst, cnt);
    dis_kernel<<<(NN + 255) / 256, 256, 0, stream>>>(cnt, dis);
    scan_block_kernel<<<NB, 256, 0, stream>>>(cnt, rs, bsums);
    scan_sums_kernel<<<1, 64, 0, stream>>>(bsums, NB);
    scan_add_kernel<<<(NN + 255) / 256, 256, 0, stream>>>(rs, bsums, cursor);
    scatter_kernel<<<EE / 256, 256, 0, stream>>>(src, dst, dis, cursor, csr);

    cvt_kernel<<<(NN * 128) / (256 * 8), 256, 0, stream>>>(x, xb);
    packw_kernel<128, 128><<<8 * 4, 64, 0, stream>>>(W1, W1p);
    packw_kernel<128, 128><<<8 * 4, 64, 0, stream>>>(W2, W2p);
    packw_kernel<128, 256><<<16 * 4, 64, 0, stream>>>(W3, W3p);
    packw_kernel<256, 128><<<8 * 8, 64, 0, stream>>>(W4, W4p);
    packw_kernel<128, 128><<<8 * 4, 64, 0, stream>>>(Wl, Wlp);

    const int AGG_GRID = (NN + 3) / 4;
    const int GX = (NN + 63) / 64;

    // conv1
    aggb_kernel<0><<<AGG_GRID, 256, 0, stream>>>(xb, dis, csr, rs, nullptr, AG);
    gemm_kernel<128, 128, false, true, true, false><<<dim3(GX, 1), 256, 0, stream>>>(AG, W1p, b1, GM);
    // conv2
    aggb_kernel<0><<<AGG_GRID, 256, 0, stream>>>(GM, dis, csr, rs, nullptr, AG);
    gemm_kernel<128, 128, false, true, true, false><<<dim3(GX, 1), 256, 0, stream>>>(AG, W2p, b2, GM);
    // conv3 (aggregate-first keeps gather at 128 channels)
    aggb_kernel<0><<<AGG_GRID, 256, 0, stream>>>(GM, dis, csr, rs, nullptr, AG);
    gemm_kernel<128, 256, false, true, true, false><<<dim3(GX, 2), 256, 0, stream>>>(AG, W3p, b3, H3);
    // conv4 (matmul-first keeps gather at 128 channels)
    gemm_kernel<256, 128, false, false, false, false><<<dim3(GX, 1), 256, 0, stream>>>(H3, W4p, nullptr, AG);
    aggb_kernel<1><<<AGG_GRID, 256, 0, stream>>>(AG, dis, csr, rs, b4, Y);
    // skip: Y += x @ Wl + bl
    gemm_kernel<128, 128, true, false, true, true><<<dim3(GX, 1), 256, 0, stream>>>(x, Wlp, bl, Y);
    // mean pool
    pool_partial_kernel<<<512, 128, 0, stream>>>(Y, batch, P);
    pool_final_kernel<<<GG, 128, 0, stream>>>(P, batch, out);
}